// Round 10
// baseline (836.813 us; speedup 1.0000x reference)
//
#include <hip/hip_runtime.h>
#include <cstdint>

// Lukasiewicz max-plus matmul: y[n,o] = max(b[o], max(0, max_i(x[n,i]+a[o,i]-1)))
// N=2048, K=512, OUT=512, fp32.
//
// R10: X via uniform VECTOR loads (L1 broadcasts one 16B txn to all lanes;
// in-order vmcnt -> pipelinable). R9 analysis: LDS broadcast is structurally
// DS-bound (one LDS unit vs 4 SIMDs; ds_read total invariant) -> drop LDS
// from the main loop entirely. A per-lane from transposed Apb (L2-resident).
// Block = 512 thr, 16 rows x 128 cols (2 cols/lane -> acc[16][2]=32 regs,
// no spill), 8-way k-split; grid (4,128)=512 blocks = 2/CU = 4 waves/SIMD.
// Merge: single 64KB LDS pass, all-static indices (rule #20).

#define NROW 2048
#define NK   512
#define NCOL 512
#define RPB  16                   // rows per block
#define CBL  128                  // cols per block (2 per lane)
#define KQ   16                   // k4-steps per wave (128 / 8 waves)
typedef float f32x4 __attribute__((ext_vector_type(4)));

// ---- prep: Apb[((o>>7)*128 + k4)*128 + (o&127)] = A[o][4k4..4k4+3] --------
__global__ __launch_bounds__(256) void luka_prep(const float* __restrict__ A,
                                                 f32x4* __restrict__ Apb) {
  int idx = blockIdx.x * 256 + threadIdx.x;   // 512 cols * 128 k4
  int o  = idx >> 7;
  int k4 = idx & 127;
  f32x4 v = *(const f32x4*)(A + o * NK + k4 * 4);      // coalesced read
  Apb[(((o >> 7) * 128) + k4) * 128 + (o & 127)] = v;  // 1MB one-shot
}

// ---- main -----------------------------------------------------------------
__global__ __launch_bounds__(512, 4) void luka_main(
    const f32x4* __restrict__ Apb, const float* __restrict__ X,
    const float* __restrict__ Bv, float* __restrict__ Y) {
  __shared__ float red[8 * RPB * CBL];   // 64KB merge buffer
  const int tid  = threadIdx.x;
  const int lane = tid & 63;
  const int w    = tid >> 6;             // wave id = K-eighth
  const int colblk  = blockIdx.x;        // 0..3
  const int rowBase = blockIdx.y * RPB;

  // Wave's A stream: cols {lane, lane+64} of colblk panel, k-eighth w.
  const f32x4* __restrict__ Aw =
      Apb + ((size_t)(colblk * 128 + w * KQ) * 128 + lane);
  // Wave's X stream: 16 rows, k4 in [w*16, w*16+16) -- wave-uniform addrs.
  // Sequential j -> 16B stride -> 7/8 L1-line hits.
  const f32x4* __restrict__ Xw =
      (const f32x4*)X + (size_t)rowBase * (NK / 4) + w * KQ;

  float acc[RPB][2];
#pragma unroll
  for (int r = 0; r < RPB; ++r) { acc[r][0] = 0.0f; acc[r][1] = 0.0f; }

  // A double-buffered in regs; X loads issued per (j,r), compiler pipelines
  // via fine-grained vmcnt (in-order returns).
  f32x4 a0 = Aw[0], a1 = Aw[64];
#pragma unroll
  for (int j = 0; j < KQ; ++j) {
    f32x4 b0, b1;
    if (j + 1 < KQ) { b0 = Aw[(j + 1) * 128]; b1 = Aw[(j + 1) * 128 + 64]; }
#pragma unroll
    for (int r = 0; r < RPB; ++r) {
      const f32x4 xv = Xw[r * (NK / 4) + j];   // uniform 16B -> L1 broadcast
      f32x4 s0 = a0 + xv;                      // v_pk_add_f32 x2
      f32x4 s1 = a1 + xv;
      acc[r][0] = fmaxf(fmaxf(s0.x, s0.y), acc[r][0]);  // v_max3
      acc[r][0] = fmaxf(fmaxf(s0.z, s0.w), acc[r][0]);
      acc[r][1] = fmaxf(fmaxf(s1.x, s1.y), acc[r][1]);
      acc[r][1] = fmaxf(fmaxf(s1.z, s1.w), acc[r][1]);
    }
    a0 = b0; a1 = b1;
  }

  // 8-way K-merge via red[8][16][128] (64KB), single pass, static indices.
#pragma unroll
  for (int r = 0; r < RPB; ++r) {
    red[(w * RPB + r) * CBL + lane]      = acc[r][0];
    red[(w * RPB + r) * CBL + 64 + lane] = acc[r][1];
  }
  __syncthreads();

  const int cc = tid & 127;              // my reduce col
  const int rr = tid >> 7;               // 0..3
  const float bv = Bv[colblk * CBL + cc];
#pragma unroll
  for (int p = 0; p < 4; ++p) {          // rows rr, rr+4, rr+8, rr+12
    const int row = p * 4 + rr;
    float m = red[row * CBL + cc];
#pragma unroll
    for (int ww = 1; ww < 8; ++ww)
      m = fmaxf(m, red[(ww * RPB + row) * CBL + cc]);
    float t = m - 1.0f;                  // defer of -1 is exact (monotone)
    Y[(size_t)(rowBase + row) * NCOL + colblk * CBL + cc] =
        fmaxf(fmaxf(t, bv), 0.0f);       // v_max3
  }
}

// ---- fallback (R1 kernel, used only if d_ws < 1MB) ------------------------
#define TILE 64
#define BK   64
__device__ __forceinline__ void async_load16(const float* g, float* l) {
  __builtin_amdgcn_global_load_lds(
      (const __attribute__((address_space(1))) void*)g,
      (__attribute__((address_space(3))) void*)l, 16, 0, 0);
}
__global__ __launch_bounds__(256) void luka_fb(
    const float* __restrict__ X, const float* __restrict__ A,
    const float* __restrict__ Bv, float* __restrict__ Y) {
  __shared__ float xs[2][TILE * BK];
  __shared__ float as[2][TILE * BK];
  const int tid = threadIdx.x, wave = tid >> 6, tx = tid & 15, ty = tid >> 4;
  const int rowBase = blockIdx.y * TILE, colBase = blockIdx.x * TILE;
  uint32_t xoff[4], aoff[4];
#pragma unroll
  for (int r = 0; r < 4; ++r) {
    int row = ty * 4 + r;
    xoff[r] = (uint32_t)row * 256u + ((uint32_t)((row & 15) ^ (row >> 2)) << 4);
  }
#pragma unroll
  for (int c = 0; c < 4; ++c) {
    int row = tx * 4 + c;
    aoff[c] = (uint32_t)row * 256u + ((uint32_t)((row & 15) ^ (row >> 2)) << 4);
  }
  float acc[4][4];
#pragma unroll
  for (int r = 0; r < 4; ++r)
#pragma unroll
    for (int c = 0; c < 4; ++c) acc[r][c] = 0.0f;
  const int row0 = tid >> 4, sl = tid & 15;
  auto stage = [&](int buf, int kt) {
#pragma unroll
    for (int j = 0; j < 4; ++j) {
      int row = row0 + j * 16;
      int m = (row & 15) ^ (row >> 2);
      int kk = ((sl ^ m) << 2);
      async_load16(X + (size_t)(rowBase + row) * NK + kt * BK + kk,
                   &xs[buf][j * 1024 + wave * 256]);
      async_load16(A + (size_t)(colBase + row) * NK + kt * BK + kk,
                   &as[buf][j * 1024 + wave * 256]);
    }
  };
  stage(0, 0);
  __syncthreads();
  int buf = 0;
#pragma unroll 1
  for (int kt = 0; kt < NK / BK; ++kt) {
    if (kt < NK / BK - 1) stage(buf ^ 1, kt + 1);
    const char* xb = (const char*)&xs[buf][0];
    const char* ab = (const char*)&as[buf][0];
#pragma unroll
    for (int s4 = 0; s4 < BK / 4; ++s4) {
      f32x4 xf[4], af[4];
#pragma unroll
      for (int r = 0; r < 4; ++r)
        xf[r] = *(const f32x4*)(xb + (xoff[r] ^ (uint32_t)(s4 << 4)));
#pragma unroll
      for (int c = 0; c < 4; ++c)
        af[c] = *(const f32x4*)(ab + (aoff[c] ^ (uint32_t)(s4 << 4)));
#pragma unroll
      for (int r = 0; r < 4; ++r)
#pragma unroll
        for (int c = 0; c < 4; ++c) {
          f32x4 s = xf[r] + af[c];
          float t0 = fmaxf(fmaxf(s.x, s.y), acc[r][c]);
          acc[r][c] = fmaxf(fmaxf(s.z, s.w), t0);
        }
    }
    __syncthreads();
    buf ^= 1;
  }
  const f32x4 bv = *(const f32x4*)&Bv[colBase + tx * 4];
  float bvv[4] = {bv.x, bv.y, bv.z, bv.w};
#pragma unroll
  for (int r = 0; r < 4; ++r) {
    f32x4 o;
    o.x = fmaxf(fmaxf(acc[r][0] - 1.0f, bvv[0]), 0.0f);
    o.y = fmaxf(fmaxf(acc[r][1] - 1.0f, bvv[1]), 0.0f);
    o.z = fmaxf(fmaxf(acc[r][2] - 1.0f, bvv[2]), 0.0f);
    o.w = fmaxf(fmaxf(acc[r][3] - 1.0f, bvv[3]), 0.0f);
    *(f32x4*)&Y[(size_t)(rowBase + ty * 4 + r) * NCOL + colBase + tx * 4] = o;
  }
}

extern "C" void kernel_launch(void* const* d_in, const int* in_sizes, int n_in,
                              void* d_out, int out_size, void* d_ws, size_t ws_size,
                              hipStream_t stream) {
  const float* X = (const float*)d_in[0];   // [2048][512]
  const float* A = (const float*)d_in[1];   // [512][512]
  const float* B = (const float*)d_in[2];   // [512]
  float* Y = (float*)d_out;                 // [2048][512]

  if (ws_size >= (size_t)NCOL * NK * sizeof(float)) {
    f32x4* Apb = (f32x4*)d_ws;
    luka_prep<<<dim3(NCOL * NK / 4 / 256), dim3(256), 0, stream>>>(A, Apb);
    dim3 grid(NCOL / CBL, NROW / RPB);      // (4, 128) = 512 blocks, 2/CU
    luka_main<<<grid, dim3(512), 0, stream>>>(Apb, X, B, Y);
  } else {
    dim3 grid(NCOL / TILE, NROW / TILE);    // fallback: R1 kernel
    luka_fb<<<grid, dim3(256), 0, stream>>>(X, A, B, Y);
  }
}

// Round 11
// 83.751 us; speedup vs baseline: 9.9917x; 9.9917x over previous
//
#include <hip/hip_runtime.h>
#include <cstdint>

// Lukasiewicz max-plus matmul: y[n,o] = max(b[o], max(0, max_i(x[n,i]+a[o,i]-1)))
// N=2048, K=512, OUT=512, fp32.
//
// R11 = R9's structure re-expressed in a 256-thread block. Empirical rule from
// R8/R9/R10: >=512-thr blocks get sandbagged to 64 VGPRs -> acc spills to
// scratch (R10: 2.6GB scratch traffic, VALU 1.9%). 256-thr blocks got 104-108
// VGPRs (R1/R2). Structure: 8 rows x 256 cols (4 cols/lane -> broadcast-X
// ds:VALU = 1:16, DS 8.2k cyc/CU < VALU 16.4k/SIMD floor), 4-way k-split
// (wave w owns k4 in [32w,32w+32), duplicate-free), X slab 16KB LDS consumed
// as wave-uniform broadcast ds_read_b128, A per-lane dbuf from transposed
// Apb, merge via one 32KB LDS pass (all-static acc indices, rule #20).
// Grid (2,256) = 512 blocks = 2/CU = 2 waves/SIMD.

#define NROW 2048
#define NK   512
#define NCOL 512
#define RPB  8                    // rows per block
#define CBL  256                  // cols per block (4 per lane)
#define KQ   32                   // k4-steps per wave (128 / 4 waves)
typedef float f32x4 __attribute__((ext_vector_type(4)));

__device__ __forceinline__ void async_load16(const float* g, float* l) {
  __builtin_amdgcn_global_load_lds(
      (const __attribute__((address_space(1))) void*)g,
      (__attribute__((address_space(3))) void*)l, 16, 0, 0);
}

// ---- prep: Apb[((o>>8)*128 + k4)*256 + (o&255)] = A[o][4k4..4k4+3] --------
__global__ __launch_bounds__(256) void luka_prep(const float* __restrict__ A,
                                                 f32x4* __restrict__ Apb) {
  int idx = blockIdx.x * 256 + threadIdx.x;   // 512 cols * 128 k4
  int o  = idx >> 7;
  int k4 = idx & 127;
  f32x4 v = *(const f32x4*)(A + o * NK + k4 * 4);      // coalesced read
  Apb[(((o >> 8) * 128) + k4) * 256 + (o & 255)] = v;  // 1MB one-shot
}

// ---- main -----------------------------------------------------------------
__global__ __launch_bounds__(256, 2) void luka_main(
    const f32x4* __restrict__ Apb, const float* __restrict__ X,
    const float* __restrict__ Bv, float* __restrict__ Y) {
  __shared__ float xsl[RPB * NK];        // 16KB X slab
  __shared__ float red[4 * RPB * CBL];   // 32KB merge buffer
  const int tid  = threadIdx.x;
  const int lane = tid & 63;
  const int w    = tid >> 6;             // wave id = K-quarter (0..3)
  const int colblk  = blockIdx.x;        // 0..1
  const int rowBase = blockIdx.y * RPB;

  // Stage X[rowBase..+8)[0..512) -> xsl row-major [8][512]; 1024 f32x4 by
  // 256 threads in 4 rounds; per-wave LDS dest linear (base + lane*16) ✓.
  {
    const float* Xg = X + (size_t)rowBase * NK;
#pragma unroll
    for (int rnd = 0; rnd < 4; ++rnd) {
      int base = rnd * 256 + w * 64;     // f32x4 index, wave-uniform
      async_load16(Xg + (size_t)(base + lane) * 4, &xsl[base * 4]);
    }
  }

  // Wave's A stream: cols {lane,+64,+128,+192} of colblk panel, k-quarter w.
  const f32x4* __restrict__ Aw =
      Apb + ((size_t)(colblk * 128 + w * KQ) * 256 + lane);

  float acc[RPB][4];
#pragma unroll
  for (int r = 0; r < RPB; ++r)
#pragma unroll
    for (int c = 0; c < 4; ++c) acc[r][c] = 0.0f;   // exact: ref clamps at 0

  // prime A double-buffer
  f32x4 a0 = Aw[0], a1 = Aw[64], a2 = Aw[128], a3 = Aw[192];

  __syncthreads();                       // staged X visible (vmcnt drain)

#pragma unroll 2
  for (int j = 0; j < KQ; ++j) {
    f32x4 n0, n1, n2, n3;
    if (j + 1 < KQ) {                    // prefetch next k4 (1-deep dbuf)
      n0 = Aw[(j + 1) * 256];
      n1 = Aw[(j + 1) * 256 + 64];
      n2 = Aw[(j + 1) * 256 + 128];
      n3 = Aw[(j + 1) * 256 + 192];
    }
    const int kb = (w * KQ + j) * 4;     // float col within x row
#pragma unroll
    for (int r = 0; r < RPB; ++r) {
      // one broadcast ds_read_b128 amortized over 4 cols (ds:VALU = 1:16)
      const f32x4 xv = *(const f32x4*)&xsl[r * NK + kb];
      f32x4 s0 = a0 + xv;                // v_pk_add_f32 x2 each
      f32x4 s1 = a1 + xv;
      f32x4 s2 = a2 + xv;
      f32x4 s3 = a3 + xv;
      acc[r][0] = fmaxf(fmaxf(s0.x, s0.y), acc[r][0]);  // v_max3
      acc[r][0] = fmaxf(fmaxf(s0.z, s0.w), acc[r][0]);
      acc[r][1] = fmaxf(fmaxf(s1.x, s1.y), acc[r][1]);
      acc[r][1] = fmaxf(fmaxf(s1.z, s1.w), acc[r][1]);
      acc[r][2] = fmaxf(fmaxf(s2.x, s2.y), acc[r][2]);
      acc[r][2] = fmaxf(fmaxf(s2.z, s2.w), acc[r][2]);
      acc[r][3] = fmaxf(fmaxf(s3.x, s3.y), acc[r][3]);
      acc[r][3] = fmaxf(fmaxf(s3.z, s3.w), acc[r][3]);
    }
    a0 = n0; a1 = n1; a2 = n2; a3 = n3;  // rename after unroll
  }

  // 4-way K-merge via red[4][8][256] (32KB), single pass, static indices.
#pragma unroll
  for (int r = 0; r < RPB; ++r)
#pragma unroll
    for (int c = 0; c < 4; ++c)
      red[(w * RPB + r) * CBL + c * 64 + lane] = acc[r][c];
  __syncthreads();

  const float bv = Bv[colblk * CBL + tid];
#pragma unroll
  for (int p = 0; p < RPB; ++p) {        // 2048 outputs / 256 thr = 8 each
    float m = fmaxf(fmaxf(red[(0 * RPB + p) * CBL + tid],
                          red[(1 * RPB + p) * CBL + tid]),
                    fmaxf(red[(2 * RPB + p) * CBL + tid],
                          red[(3 * RPB + p) * CBL + tid]));
    float t = m - 1.0f;                  // defer of -1 is exact (monotone)
    Y[(size_t)(rowBase + p) * NCOL + colblk * CBL + tid] =
        fmaxf(fmaxf(t, bv), 0.0f);       // v_max3
  }
}

// ---- fallback (R1 kernel, used only if d_ws < 1MB) ------------------------
#define TILE 64
#define BK   64
__global__ __launch_bounds__(256) void luka_fb(
    const float* __restrict__ X, const float* __restrict__ A,
    const float* __restrict__ Bv, float* __restrict__ Y) {
  __shared__ float xs[2][TILE * BK];
  __shared__ float as[2][TILE * BK];
  const int tid = threadIdx.x, wave = tid >> 6, tx = tid & 15, ty = tid >> 4;
  const int rowBase = blockIdx.y * TILE, colBase = blockIdx.x * TILE;
  uint32_t xoff[4], aoff[4];
#pragma unroll
  for (int r = 0; r < 4; ++r) {
    int row = ty * 4 + r;
    xoff[r] = (uint32_t)row * 256u + ((uint32_t)((row & 15) ^ (row >> 2)) << 4);
  }
#pragma unroll
  for (int c = 0; c < 4; ++c) {
    int row = tx * 4 + c;
    aoff[c] = (uint32_t)row * 256u + ((uint32_t)((row & 15) ^ (row >> 2)) << 4);
  }
  float acc[4][4];
#pragma unroll
  for (int r = 0; r < 4; ++r)
#pragma unroll
    for (int c = 0; c < 4; ++c) acc[r][c] = 0.0f;
  const int row0 = tid >> 4, sl = tid & 15;
  auto stage = [&](int buf, int kt) {
#pragma unroll
    for (int j = 0; j < 4; ++j) {
      int row = row0 + j * 16;
      int m = (row & 15) ^ (row >> 2);
      int kk = ((sl ^ m) << 2);
      async_load16(X + (size_t)(rowBase + row) * NK + kt * BK + kk,
                   &xs[buf][j * 1024 + wave * 256]);
      async_load16(A + (size_t)(colBase + row) * NK + kt * BK + kk,
                   &as[buf][j * 1024 + wave * 256]);
    }
  };
  stage(0, 0);
  __syncthreads();
  int buf = 0;
#pragma unroll 1
  for (int kt = 0; kt < NK / BK; ++kt) {
    if (kt < NK / BK - 1) stage(buf ^ 1, kt + 1);
    const char* xb = (const char*)&xs[buf][0];
    const char* ab = (const char*)&as[buf][0];
#pragma unroll
    for (int s4 = 0; s4 < BK / 4; ++s4) {
      f32x4 xf[4], af[4];
#pragma unroll
      for (int r = 0; r < 4; ++r)
        xf[r] = *(const f32x4*)(xb + (xoff[r] ^ (uint32_t)(s4 << 4)));
#pragma unroll
      for (int c = 0; c < 4; ++c)
        af[c] = *(const f32x4*)(ab + (aoff[c] ^ (uint32_t)(s4 << 4)));
#pragma unroll
      for (int r = 0; r < 4; ++r)
#pragma unroll
        for (int c = 0; c < 4; ++c) {
          f32x4 s = xf[r] + af[c];
          float t0 = fmaxf(fmaxf(s.x, s.y), acc[r][c]);
          acc[r][c] = fmaxf(fmaxf(s.z, s.w), t0);
        }
    }
    __syncthreads();
    buf ^= 1;
  }
  const f32x4 bv = *(const f32x4*)&Bv[colBase + tx * 4];
  float bvv[4] = {bv.x, bv.y, bv.z, bv.w};
#pragma unroll
  for (int r = 0; r < 4; ++r) {
    f32x4 o;
    o.x = fmaxf(fmaxf(acc[r][0] - 1.0f, bvv[0]), 0.0f);
    o.y = fmaxf(fmaxf(acc[r][1] - 1.0f, bvv[1]), 0.0f);
    o.z = fmaxf(fmaxf(acc[r][2] - 1.0f, bvv[2]), 0.0f);
    o.w = fmaxf(fmaxf(acc[r][3] - 1.0f, bvv[3]), 0.0f);
    *(f32x4*)&Y[(size_t)(rowBase + ty * 4 + r) * NCOL + colBase + tx * 4] = o;
  }
}

extern "C" void kernel_launch(void* const* d_in, const int* in_sizes, int n_in,
                              void* d_out, int out_size, void* d_ws, size_t ws_size,
                              hipStream_t stream) {
  const float* X = (const float*)d_in[0];   // [2048][512]
  const float* A = (const float*)d_in[1];   // [512][512]
  const float* B = (const float*)d_in[2];   // [512]
  float* Y = (float*)d_out;                 // [2048][512]

  if (ws_size >= (size_t)NCOL * NK * sizeof(float)) {
    f32x4* Apb = (f32x4*)d_ws;
    luka_prep<<<dim3(NCOL * NK / 4 / 256), dim3(256), 0, stream>>>(A, Apb);
    dim3 grid(NCOL / CBL, NROW / RPB);      // (2, 256) = 512 blocks, 2/CU
    luka_main<<<grid, dim3(256), 0, stream>>>(Apb, X, B, Y);
  } else {
    dim3 grid(NCOL / TILE, NROW / TILE);    // fallback: R1 kernel
    luka_fb<<<grid, dim3(256), 0, stream>>>(X, A, B, Y);
  }
}